// Round 1
// baseline (993.886 us; speedup 1.0000x reference)
//
#include <hip/hip_runtime.h>
#include <hip/hip_bf16.h>
#include <math.h>

// ---------- types ----------
typedef __bf16 bf16x8 __attribute__((ext_vector_type(8)));
typedef float  f32x4  __attribute__((ext_vector_type(4)));

struct __align__(8) bf16x4s { __hip_bfloat16 a, b, c, d; };

__device__ __forceinline__ void gload_lds16(const void* g, void* l) {
  __builtin_amdgcn_global_load_lds(
      (const __attribute__((address_space(1))) void*)g,
      (__attribute__((address_space(3))) void*)l, 16, 0, 0);
}

// ---------- GEMM: C[M,N] = A[M,K](bf16,row) * B[N,K]^T(bf16,row), fused epilogues ----------
// EPI 0: u1' = bf16( W[b,p] * gelu(acc + b1[p,e]) )          (p = n>>10, b = m>>5)
// EPI 1: h  += acc + wb2[b,n]; write h f32 + h bf16
// EPI 2: out = acc (f32)
template<int BM, int BN, int EPI>
__global__ __launch_bounds__(256)
void gemm_nt(const __hip_bfloat16* __restrict__ A,
             const __hip_bfloat16* __restrict__ B,
             const int K, const int N,
             const float* __restrict__ p0,   // EPI0: b1[P,1024]   EPI1: wb2[B,1024]
             const float* __restrict__ p1,   // EPI0: W[B,P]
             float* __restrict__ f32out,     // EPI1: h (rmw)      EPI2: out
             __hip_bfloat16* __restrict__ bfout) // EPI0: u1, EPI1: hb
{
  __shared__ __align__(16) __hip_bfloat16 sA[BM * 64];
  __shared__ __align__(16) __hip_bfloat16 sB[BN * 64];
  constexpr int WR = BM / 2, WC = BN / 2;
  constexpr int MI = WR / 16, NJ = WC / 16;
  constexpr int CPA = BM / 32, CPB = BN / 32;  // 1KB staging chunks per wave

  const int tid = threadIdx.x;
  const int lane = tid & 63, wid = tid >> 6;
  const int l15 = lane & 15, l4 = lane >> 4;
  const int r8 = lane >> 3, blk = lane & 7;
  const long m0 = (long)blockIdx.y * BM;
  const long n0 = (long)blockIdx.x * BN;
  const int wr = (wid >> 1) * WR, wc = (wid & 1) * WC;

  f32x4 acc[MI][NJ] = {};

  for (int k0 = 0; k0 < K; k0 += 64) {
    __syncthreads();
    // stage A tile [BM][64] with 16B-block XOR swizzle applied on the GLOBAL side
#pragma unroll
    for (int c = 0; c < CPA; ++c) {
      int ch = wid * CPA + c;
      int row = ch * 8 + r8;
      gload_lds16(A + (m0 + row) * (long)K + k0 + ((blk ^ r8) << 3), sA + ch * 512);
    }
#pragma unroll
    for (int c = 0; c < CPB; ++c) {
      int ch = wid * CPB + c;
      int row = ch * 8 + r8;
      gload_lds16(B + (n0 + row) * (long)K + k0 + ((blk ^ r8) << 3), sB + ch * 512);
    }
    __syncthreads();
#pragma unroll
    for (int kk = 0; kk < 2; ++kk) {
      bf16x8 af[MI], bfr[NJ];
#pragma unroll
      for (int mi = 0; mi < MI; ++mi) {
        int row = wr + mi * 16 + l15;
        af[mi] = *(const bf16x8*)(sA + row * 64 + (((kk * 4 + l4) ^ (row & 7)) << 3));
      }
#pragma unroll
      for (int nj = 0; nj < NJ; ++nj) {
        int row = wc + nj * 16 + l15;
        bfr[nj] = *(const bf16x8*)(sB + row * 64 + (((kk * 4 + l4) ^ (row & 7)) << 3));
      }
#pragma unroll
      for (int mi = 0; mi < MI; ++mi)
#pragma unroll
        for (int nj = 0; nj < NJ; ++nj)
          acc[mi][nj] = __builtin_amdgcn_mfma_f32_16x16x32_bf16(af[mi], bfr[nj], acc[mi][nj], 0, 0, 0);
    }
  }

  // epilogue: D[row=(l>>4)*4+r][col=l&15] per 16x16 frag (m89-verified layout)
#pragma unroll
  for (int mi = 0; mi < MI; ++mi)
#pragma unroll
    for (int nj = 0; nj < NJ; ++nj) {
      long gn = n0 + wc + nj * 16 + l15;
#pragma unroll
      for (int r = 0; r < 4; ++r) {
        long gm = m0 + wr + mi * 16 + l4 * 4 + r;
        float v = acc[mi][nj][r];
        if constexpr (EPI == 0) {
          int p = (int)(gn >> 10), e = (int)(gn & 1023);
          int b = (int)(gm >> 5);
          v += p0[(p << 10) + e];
          v = 0.5f * v * (1.0f + erff(v * 0.70710678118654752f));
          v *= p1[(b << 3) + p];
          bfout[gm * (long)N + gn] = __float2bfloat16(v);
        } else if constexpr (EPI == 1) {
          int b = (int)(gm >> 5);
          long idx = gm * (long)N + gn;
          v += p0[(b << 10) + (int)gn] + f32out[idx];
          f32out[idx] = v;
          bfout[idx] = __float2bfloat16(v);
        } else {
          f32out[gm * (long)N + gn] = v;
        }
      }
    }
}

// ---------- small kernels ----------
__global__ void cvt_bf16_k(const float* __restrict__ in, __hip_bfloat16* __restrict__ out, long n) {
  long i = ((long)blockIdx.x * blockDim.x + threadIdx.x) * 4;
  if (i >= n) return;
  float4 v = *(const float4*)(in + i);
  *(bf16x4s*)(out + i) = bf16x4s{__float2bfloat16(v.x), __float2bfloat16(v.y),
                                 __float2bfloat16(v.z), __float2bfloat16(v.w)};
}

// out[c*out_rs + p*out_bs + r] = bf16(in[p*in_bs + r*1024 + c]), R=C=1024 tiles of 32x32
__global__ void tconv_k(const float* __restrict__ in, __hip_bfloat16* __restrict__ out,
                        long in_bs, long out_rs, long out_bs) {
  __shared__ float tile[32][33];
  int p = blockIdx.z;
  int r0 = blockIdx.y * 32, c0 = blockIdx.x * 32;
  int tx = threadIdx.x, ty = threadIdx.y;
#pragma unroll
  for (int i = 0; i < 32; i += 8)
    tile[ty + i][tx] = in[(long)p * in_bs + (long)(r0 + ty + i) * 1024 + c0 + tx];
  __syncthreads();
#pragma unroll
  for (int i = 0; i < 32; i += 8)
    out[(long)(c0 + ty + i) * out_rs + (long)p * out_bs + (r0 + tx)] =
        __float2bfloat16(tile[tx][ty + i]);
}

__global__ void embed_k(const int* __restrict__ x, const float* __restrict__ emb,
                        const float* __restrict__ pos, float* __restrict__ h,
                        __hip_bfloat16* __restrict__ hb, float* __restrict__ divp) {
  int row = blockIdx.x;          // b*32 + t
  int t = row & 31;
  int c = threadIdx.x * 4;
  long tok = x[row];
  float4 e = *(const float4*)(emb + tok * 1024 + c);
  float4 q = *(const float4*)(pos + (long)t * 1024 + c);
  float4 v{e.x + q.x, e.y + q.y, e.z + q.z, e.w + q.w};
  *(float4*)(h + (long)row * 1024 + c) = v;
  *(bf16x4s*)(hb + (long)row * 1024 + c) =
      bf16x4s{__float2bfloat16(v.x), __float2bfloat16(v.y),
              __float2bfloat16(v.z), __float2bfloat16(v.w)};
  if (row == 0 && threadIdx.x == 0) *divp = 0.f;
}

__global__ void select_k(const float* __restrict__ h, const float* __restrict__ selw,
                         const float* __restrict__ selb, const float* __restrict__ gum,
                         float* __restrict__ W, int dep) {
  int b = blockIdx.x, tid = threadIdx.x;
  int c = tid * 4;
  float4 s{0.f, 0.f, 0.f, 0.f};
  for (int t = 0; t < 32; ++t) {
    const float4 v = *(const float4*)(h + ((long)(b * 32 + t)) * 1024 + c);
    s.x += v.x; s.y += v.y; s.z += v.z; s.w += v.w;
  }
  float lp[8];
#pragma unroll
  for (int p = 0; p < 8; ++p) {
    const float4 w = *(const float4*)(selw + dep * 8192 + p * 1024 + c);
    lp[p] = (s.x * w.x + s.y * w.y + s.z * w.z + s.w * w.w) * (1.f / 32.f);
  }
  int lane = tid & 63, wid = tid >> 6;
#pragma unroll
  for (int p = 0; p < 8; ++p)
    for (int o = 32; o; o >>= 1) lp[p] += __shfl_down(lp[p], o);
  __shared__ float red[4][8];
  if (lane == 0) {
#pragma unroll
    for (int p = 0; p < 8; ++p) red[wid][p] = lp[p];
  }
  __syncthreads();
  if (tid == 0) {
    float lg[8], mx = -1e30f;
    for (int p = 0; p < 8; ++p) {
      lg[p] = red[0][p] + red[1][p] + red[2][p] + red[3][p]
            + selb[dep * 8 + p] + gum[dep * 512 + b * 8 + p];
      mx = fmaxf(mx, lg[p]);
    }
    float sm = 0.f;
    for (int p = 0; p < 8; ++p) { lg[p] = expf(lg[p] - mx); sm += lg[p]; }
    float inv = 1.f / sm;
    for (int p = 0; p < 8; ++p) W[b * 8 + p] = lg[p] * inv;
  }
}

__global__ void div_k(const float* __restrict__ W, float* __restrict__ divp) {
  int b = threadIdx.x;  // 64 threads
  float w[8];
#pragma unroll
  for (int p = 0; p < 8; ++p) w[p] = W[b * 8 + p];
#pragma unroll
  for (int p = 0; p < 8; ++p)
    for (int o = 32; o; o >>= 1) w[p] += __shfl_down(w[p], o);
  if (b == 0) {
    float d = *divp;
    const float u = 0.125f;
    const float lu = logf(0.125f);
    for (int p = 0; p < 8; ++p) d += u * (lu - logf(w[p] * (1.f / 64.f)));
    *divp = d;
  }
}

__global__ void wb2_k(const float* __restrict__ W, const float* __restrict__ b2,
                      float* __restrict__ wb2) {
  int b = blockIdx.x;
  int c = threadIdx.x * 4;
  float4 a{0.f, 0.f, 0.f, 0.f};
#pragma unroll
  for (int p = 0; p < 8; ++p) {
    float wp = W[b * 8 + p];
    const float4 v = *(const float4*)(b2 + p * 1024 + c);
    a.x += wp * v.x; a.y += wp * v.y; a.z += wp * v.z; a.w += wp * v.w;
  }
  *(float4*)(wb2 + (long)b * 1024 + c) = a;
}

__global__ void ln_k(const float* __restrict__ h, const float* __restrict__ g,
                     const float* __restrict__ be, __hip_bfloat16* __restrict__ hnb,
                     const float* __restrict__ divp, float* __restrict__ divout) {
  int row = blockIdx.x, tid = threadIdx.x;
  int c = tid * 4;
  const float4 v = *(const float4*)(h + (long)row * 1024 + c);
  float s = v.x + v.y + v.z + v.w;
  float q = v.x * v.x + v.y * v.y + v.z * v.z + v.w * v.w;
  for (int o = 32; o; o >>= 1) { s += __shfl_down(s, o); q += __shfl_down(q, o); }
  __shared__ float red[16];
  int lane = tid & 63, wid = tid >> 6;
  if (lane == 0) { red[wid] = s; red[8 + wid] = q; }
  __syncthreads();
  if (tid == 0) {
    float S = red[0] + red[1] + red[2] + red[3];
    float Q = red[8] + red[9] + red[10] + red[11];
    float mu = S * (1.f / 1024.f);
    float var = Q * (1.f / 1024.f) - mu * mu;
    red[0] = mu; red[1] = rsqrtf(var + 1e-5f);
  }
  __syncthreads();
  float mu = red[0], rs = red[1];
  float4 gg = *(const float4*)(g + c), bb = *(const float4*)(be + c);
  *(bf16x4s*)(hnb + (long)row * 1024 + c) =
      bf16x4s{__float2bfloat16((v.x - mu) * rs * gg.x + bb.x),
              __float2bfloat16((v.y - mu) * rs * gg.y + bb.y),
              __float2bfloat16((v.z - mu) * rs * gg.z + bb.z),
              __float2bfloat16((v.w - mu) * rs * gg.w + bb.w)};
  if (row == 0 && tid == 0) *divout = *divp;
}

// ---------- launch ----------
extern "C" void kernel_launch(void* const* d_in, const int* in_sizes, int n_in,
                              void* d_out, int out_size, void* d_ws, size_t ws_size,
                              hipStream_t stream) {
  (void)in_sizes; (void)n_in; (void)out_size; (void)ws_size;
  const int*   x     = (const int*)  d_in[0];
  const float* emb   = (const float*)d_in[1];
  const float* pos   = (const float*)d_in[2];
  const float* w1    = (const float*)d_in[3];
  const float* b1    = (const float*)d_in[4];
  const float* w2    = (const float*)d_in[5];
  const float* b2    = (const float*)d_in[6];
  const float* selw  = (const float*)d_in[7];
  const float* selb  = (const float*)d_in[8];
  const float* lng   = (const float*)d_in[9];
  const float* lnb   = (const float*)d_in[10];
  const float* headw = (const float*)d_in[11];
  const float* gum   = (const float*)d_in[12];
  float* out = (float*)d_out;

  char* ws = (char*)d_ws;
  __hip_bfloat16* w1t   = (__hip_bfloat16*)(ws);               // [8192,1024] bf16  16 MiB
  __hip_bfloat16* w2t   = (__hip_bfloat16*)(ws + 16777216);    // [1024,8192] bf16  16 MiB
  __hip_bfloat16* headb = (__hip_bfloat16*)(ws + 33554432);    // [32000,1024] bf16 62.5 MiB
  float*          h     = (float*)(ws + 99090432);             // [2048,1024] f32   8 MiB
  __hip_bfloat16* hb    = (__hip_bfloat16*)(ws + 107479040);   // [2048,1024] bf16  4 MiB
  __hip_bfloat16* u1    = (__hip_bfloat16*)(ws + 111673344);   // [2048,8192] bf16  32 MiB
  float*          W     = (float*)(ws + 145227776);            // [64,8]
  float*          wb2   = (float*)(ws + 145229824);            // [64,1024]
  float*          divp  = (float*)(ws + 145491968);            // scalar

  cvt_bf16_k<<<32000, 256, 0, stream>>>(headw, headb, 32768000L);
  tconv_k<<<dim3(32, 32, 8), dim3(32, 8), 0, stream>>>(w1, w1t, 1L << 20, 1024L, 1L << 20);
  tconv_k<<<dim3(32, 32, 8), dim3(32, 8), 0, stream>>>(w2, w2t, 1L << 20, 8192L, 1024L);
  embed_k<<<2048, 256, 0, stream>>>(x, emb, pos, h, hb, divp);

  for (int d = 0; d < 4; ++d) {
    select_k<<<64, 256, 0, stream>>>(h, selw, selb, gum, W, d);
    div_k<<<1, 64, 0, stream>>>(W, divp);
    wb2_k<<<64, 256, 0, stream>>>(W, b2, wb2);
    // u1' = W * gelu(h @ w1 + b1)   : M=2048 N=8192 K=1024
    gemm_nt<128, 128, 0><<<dim3(64, 16), 256, 0, stream>>>(hb, w1t, 1024, 8192, b1, W, nullptr, u1);
    // h += u1' @ w2 + wb2           : M=2048 N=1024 K=8192
    gemm_nt<64, 128, 1><<<dim3(8, 32), 256, 0, stream>>>(u1, w2t, 8192, 1024, wb2, nullptr, h, hb);
  }

  ln_k<<<2048, 256, 0, stream>>>(h, lng, lnb, hb, divp, out + 65536000L);
  // logits = hn @ head_w^T          : M=2048 N=32000 K=1024
  gemm_nt<128, 128, 2><<<dim3(250, 16), 256, 0, stream>>>(hb, headb, 1024, 32000, nullptr, nullptr, out, nullptr);
}

// Round 2
// 794.043 us; speedup vs baseline: 1.2517x; 1.2517x over previous
//
#include <hip/hip_runtime.h>
#include <hip/hip_bf16.h>
#include <math.h>

// ---------- types ----------
typedef __bf16 bf16x8 __attribute__((ext_vector_type(8)));
typedef float  f32x4  __attribute__((ext_vector_type(4)));

struct __align__(8) bf16x4s { __hip_bfloat16 a, b, c, d; };

__device__ __forceinline__ void gload_lds16(const void* g, void* l) {
  __builtin_amdgcn_global_load_lds(
      (const __attribute__((address_space(1))) void*)g,
      (__attribute__((address_space(3))) void*)l, 16, 0, 0);
}

__device__ __forceinline__ float fast_gelu(float v) {
  // gelu(v) = 0.5 v (1 + erf(v/sqrt2)), erf via A&S 7.1.26 (|err|<=1.5e-7), branchless
  float s = 0.70710678118654752f * v;
  float a = fabsf(s);
  float t = __builtin_amdgcn_rcpf(fmaf(0.3275911f, a, 1.0f));
  float p = t * fmaf(t, fmaf(t, fmaf(t, fmaf(t, 1.061405429f, -1.453152027f),
                                     1.421413741f), -0.284496736f), 0.254829592f);
  float e = __expf(-a * a);
  float er = copysignf(fmaf(-p, e, 1.0f), s);
  return 0.5f * v * (1.0f + er);
}

// ---------- GEMM: C[M,N] = A[M,K](bf16,row) * B[N,K]^T(bf16,row) ----------
// grid: x = M-blocks (fastest -> consecutive blocks share a B panel),
//       y = N-blocks, z = K-split (EPI2 writes to per-z slab)
// EPI 0: u1' = bf16( W[b,p] * gelu(acc + b1[p,e]) )   (p=n>>10, b=m>>5)
// EPI 2: f32out[slab + m*N + n] = acc
template<int BM, int BN, int EPI>
__global__ __launch_bounds__(256)
void gemm_nt(const __hip_bfloat16* __restrict__ A,
             const __hip_bfloat16* __restrict__ B,
             const int K, const int Kc, const int N,
             const float* __restrict__ p0,   // EPI0: b1[P,1024]
             const float* __restrict__ p1,   // EPI0: W[B,P]
             float* __restrict__ f32out,     // EPI2: out/partials
             __hip_bfloat16* __restrict__ bfout) // EPI0: u1
{
  __shared__ __align__(16) __hip_bfloat16 sA[BM * 64];
  __shared__ __align__(16) __hip_bfloat16 sB[BN * 64];
  constexpr int WR = BM / 2, WC = BN / 2;
  constexpr int MI = WR / 16, NJ = WC / 16;
  constexpr int CPA = BM / 32, CPB = BN / 32;  // 1KB staging chunks per wave

  const int tid = threadIdx.x;
  const int lane = tid & 63, wid = tid >> 6;
  const int l15 = lane & 15, l4 = lane >> 4;
  const int r8 = lane >> 3, blk = lane & 7;
  const long m0 = (long)blockIdx.x * BM;
  const long n0 = (long)blockIdx.y * BN;
  const int kbeg = blockIdx.z * Kc;
  const int wr = (wid >> 1) * WR, wc = (wid & 1) * WC;

  f32x4 acc[MI][NJ] = {};

  for (int k0 = kbeg; k0 < kbeg + Kc; k0 += 64) {
    __syncthreads();
    // stage tiles [rows][64] with 16B-block XOR swizzle applied on the GLOBAL side
#pragma unroll
    for (int c = 0; c < CPA; ++c) {
      int ch = wid * CPA + c;
      int row = ch * 8 + r8;
      gload_lds16(A + (m0 + row) * (long)K + k0 + ((blk ^ r8) << 3), sA + ch * 512);
    }
#pragma unroll
    for (int c = 0; c < CPB; ++c) {
      int ch = wid * CPB + c;
      int row = ch * 8 + r8;
      gload_lds16(B + (n0 + row) * (long)K + k0 + ((blk ^ r8) << 3), sB + ch * 512);
    }
    __syncthreads();
#pragma unroll
    for (int kk = 0; kk < 2; ++kk) {
      bf16x8 af[MI], bfr[NJ];
#pragma unroll
      for (int mi = 0; mi < MI; ++mi) {
        int row = wr + mi * 16 + l15;
        af[mi] = *(const bf16x8*)(sA + row * 64 + (((kk * 4 + l4) ^ (row & 7)) << 3));
      }
#pragma unroll
      for (int nj = 0; nj < NJ; ++nj) {
        int row = wc + nj * 16 + l15;
        bfr[nj] = *(const bf16x8*)(sB + row * 64 + (((kk * 4 + l4) ^ (row & 7)) << 3));
      }
#pragma unroll
      for (int mi = 0; mi < MI; ++mi)
#pragma unroll
        for (int nj = 0; nj < NJ; ++nj)
          acc[mi][nj] = __builtin_amdgcn_mfma_f32_16x16x32_bf16(af[mi], bfr[nj], acc[mi][nj], 0, 0, 0);
    }
  }

  // epilogue: D[row=(l>>4)*4+r][col=l&15] per 16x16 frag (m89-verified layout)
  const long slab = (EPI == 2) ? (long)blockIdx.z * (long)(gridDim.x * BM) * N : 0;
#pragma unroll
  for (int mi = 0; mi < MI; ++mi) {
    const long gmb = m0 + wr + mi * 16 + l4 * 4;   // rows gmb..gmb+3 (same batch b)
    const int b = (int)(gmb >> 5);
#pragma unroll
    for (int nj = 0; nj < NJ; ++nj) {
      const long gn = n0 + wc + nj * 16 + l15;
      if constexpr (EPI == 0) {
        const int p = (int)(gn >> 10), e = (int)(gn & 1023);
        const float bias = p0[(p << 10) + e];
        const float wpb = p1[(b << 3) + p];
#pragma unroll
        for (int r = 0; r < 4; ++r) {
          float v = fast_gelu(acc[mi][nj][r] + bias) * wpb;
          bfout[(gmb + r) * (long)N + gn] = __float2bfloat16(v);
        }
      } else {
#pragma unroll
        for (int r = 0; r < 4; ++r)
          f32out[slab + (gmb + r) * (long)N + gn] = acc[mi][nj][r];
      }
    }
  }
}

// ---------- small kernels ----------
__global__ void cvt_bf16_k(const float* __restrict__ in, __hip_bfloat16* __restrict__ out, long n) {
  long i = ((long)blockIdx.x * blockDim.x + threadIdx.x) * 4;
  if (i >= n) return;
  float4 v = *(const float4*)(in + i);
  *(bf16x4s*)(out + i) = bf16x4s{__float2bfloat16(v.x), __float2bfloat16(v.y),
                                 __float2bfloat16(v.z), __float2bfloat16(v.w)};
}

// out[c*out_rs + p*out_bs + r] = bf16(in[p*in_bs + r*1024 + c]), tiles of 32x32
__global__ void tconv_k(const float* __restrict__ in, __hip_bfloat16* __restrict__ out,
                        long in_bs, long out_rs, long out_bs) {
  __shared__ float tile[32][33];
  int p = blockIdx.z;
  int r0 = blockIdx.y * 32, c0 = blockIdx.x * 32;
  int tx = threadIdx.x, ty = threadIdx.y;
#pragma unroll
  for (int i = 0; i < 32; i += 8)
    tile[ty + i][tx] = in[(long)p * in_bs + (long)(r0 + ty + i) * 1024 + c0 + tx];
  __syncthreads();
#pragma unroll
  for (int i = 0; i < 32; i += 8)
    out[(long)(c0 + ty + i) * out_rs + (long)p * out_bs + (r0 + tx)] =
        __float2bfloat16(tile[tx][ty + i]);
}

__global__ void embed_k(const int* __restrict__ x, const float* __restrict__ emb,
                        const float* __restrict__ pos, float* __restrict__ h,
                        __hip_bfloat16* __restrict__ hb, float* __restrict__ divp) {
  int row = blockIdx.x;          // b*32 + t
  int t = row & 31;
  int c = threadIdx.x * 4;
  long tok = x[row];
  float4 e = *(const float4*)(emb + tok * 1024 + c);
  float4 q = *(const float4*)(pos + (long)t * 1024 + c);
  float4 v{e.x + q.x, e.y + q.y, e.z + q.z, e.w + q.w};
  *(float4*)(h + (long)row * 1024 + c) = v;
  *(bf16x4s*)(hb + (long)row * 1024 + c) =
      bf16x4s{__float2bfloat16(v.x), __float2bfloat16(v.y),
              __float2bfloat16(v.z), __float2bfloat16(v.w)};
  if (row == 0 && threadIdx.x == 0) *divp = 0.f;
}

__global__ void select_k(const float* __restrict__ h, const float* __restrict__ selw,
                         const float* __restrict__ selb, const float* __restrict__ gum,
                         float* __restrict__ W, int dep) {
  int b = blockIdx.x, tid = threadIdx.x;
  int c = tid * 4;
  float4 s{0.f, 0.f, 0.f, 0.f};
  for (int t = 0; t < 32; ++t) {
    const float4 v = *(const float4*)(h + ((long)(b * 32 + t)) * 1024 + c);
    s.x += v.x; s.y += v.y; s.z += v.z; s.w += v.w;
  }
  float lp[8];
#pragma unroll
  for (int p = 0; p < 8; ++p) {
    const float4 w = *(const float4*)(selw + dep * 8192 + p * 1024 + c);
    lp[p] = (s.x * w.x + s.y * w.y + s.z * w.z + s.w * w.w) * (1.f / 32.f);
  }
  int lane = tid & 63, wid = tid >> 6;
#pragma unroll
  for (int p = 0; p < 8; ++p)
    for (int o = 32; o; o >>= 1) lp[p] += __shfl_down(lp[p], o);
  __shared__ float red[4][8];
  if (lane == 0) {
#pragma unroll
    for (int p = 0; p < 8; ++p) red[wid][p] = lp[p];
  }
  __syncthreads();
  if (tid == 0) {
    float lg[8], mx = -1e30f;
    for (int p = 0; p < 8; ++p) {
      lg[p] = red[0][p] + red[1][p] + red[2][p] + red[3][p]
            + selb[dep * 8 + p] + gum[dep * 512 + b * 8 + p];
      mx = fmaxf(mx, lg[p]);
    }
    float sm = 0.f;
    for (int p = 0; p < 8; ++p) { lg[p] = expf(lg[p] - mx); sm += lg[p]; }
    float inv = 1.f / sm;
    for (int p = 0; p < 8; ++p) W[b * 8 + p] = lg[p] * inv;
  }
}

// wb2[b,:] = sum_p W[b,p]*b2[p,:]; block 0 thread 0 also accumulates KL div term
__global__ void wb2_k(const float* __restrict__ W, const float* __restrict__ b2,
                      float* __restrict__ wb2, float* __restrict__ divp) {
  int b = blockIdx.x;
  int c = threadIdx.x * 4;
  float4 a{0.f, 0.f, 0.f, 0.f};
#pragma unroll
  for (int p = 0; p < 8; ++p) {
    float wp = W[b * 8 + p];
    const float4 v = *(const float4*)(b2 + p * 1024 + c);
    a.x += wp * v.x; a.y += wp * v.y; a.z += wp * v.z; a.w += wp * v.w;
  }
  *(float4*)(wb2 + (long)b * 1024 + c) = a;
  if (b == 0 && threadIdx.x == 0) {
    float s[8] = {0.f, 0.f, 0.f, 0.f, 0.f, 0.f, 0.f, 0.f};
    for (int bb = 0; bb < 64; ++bb)
#pragma unroll
      for (int p = 0; p < 8; ++p) s[p] += W[bb * 8 + p];
    float d = *divp;
    const float u = 0.125f, lu = logf(0.125f);
#pragma unroll
    for (int p = 0; p < 8; ++p) d += u * (lu - logf(s[p] * (1.f / 64.f)));
    *divp = d;
  }
}

// h += wb2 + sum_s part[s]; write h f32 + bf16
__global__ void h_update_k(const float* __restrict__ part, float* __restrict__ h,
                           const float* __restrict__ wb2, __hip_bfloat16* __restrict__ hb) {
  int row = blockIdx.x;
  int c = threadIdx.x * 4;
  long idx = (long)row * 1024 + c;
  float4 a = *(const float4*)(h + idx);
  const float4 w = *(const float4*)(wb2 + (long)(row >> 5) * 1024 + c);
  a.x += w.x; a.y += w.y; a.z += w.z; a.w += w.w;
#pragma unroll
  for (int s = 0; s < 4; ++s) {
    const float4 v = *(const float4*)(part + (long)s * 2097152 + idx);
    a.x += v.x; a.y += v.y; a.z += v.z; a.w += v.w;
  }
  *(float4*)(h + idx) = a;
  *(bf16x4s*)(hb + idx) = bf16x4s{__float2bfloat16(a.x), __float2bfloat16(a.y),
                                  __float2bfloat16(a.z), __float2bfloat16(a.w)};
}

__global__ void ln_k(const float* __restrict__ h, const float* __restrict__ g,
                     const float* __restrict__ be, __hip_bfloat16* __restrict__ hnb,
                     const float* __restrict__ divp, float* __restrict__ divout) {
  int row = blockIdx.x, tid = threadIdx.x;
  int c = tid * 4;
  const float4 v = *(const float4*)(h + (long)row * 1024 + c);
  float s = v.x + v.y + v.z + v.w;
  float q = v.x * v.x + v.y * v.y + v.z * v.z + v.w * v.w;
  for (int o = 32; o; o >>= 1) { s += __shfl_down(s, o); q += __shfl_down(q, o); }
  __shared__ float red[16];
  int lane = tid & 63, wid = tid >> 6;
  if (lane == 0) { red[wid] = s; red[8 + wid] = q; }
  __syncthreads();
  if (tid == 0) {
    float S = red[0] + red[1] + red[2] + red[3];
    float Q = red[8] + red[9] + red[10] + red[11];
    float mu = S * (1.f / 1024.f);
    float var = Q * (1.f / 1024.f) - mu * mu;
    red[0] = mu; red[1] = rsqrtf(var + 1e-5f);
  }
  __syncthreads();
  float mu = red[0], rs = red[1];
  float4 gg = *(const float4*)(g + c), bb = *(const float4*)(be + c);
  *(bf16x4s*)(hnb + (long)row * 1024 + c) =
      bf16x4s{__float2bfloat16((v.x - mu) * rs * gg.x + bb.x),
              __float2bfloat16((v.y - mu) * rs * gg.y + bb.y),
              __float2bfloat16((v.z - mu) * rs * gg.z + bb.z),
              __float2bfloat16((v.w - mu) * rs * gg.w + bb.w)};
  if (row == 0 && tid == 0) *divout = *divp;
}

// ---------- launch ----------
extern "C" void kernel_launch(void* const* d_in, const int* in_sizes, int n_in,
                              void* d_out, int out_size, void* d_ws, size_t ws_size,
                              hipStream_t stream) {
  (void)in_sizes; (void)n_in; (void)out_size; (void)ws_size;
  const int*   x     = (const int*)  d_in[0];
  const float* emb   = (const float*)d_in[1];
  const float* pos   = (const float*)d_in[2];
  const float* w1    = (const float*)d_in[3];
  const float* b1    = (const float*)d_in[4];
  const float* w2    = (const float*)d_in[5];
  const float* b2    = (const float*)d_in[6];
  const float* selw  = (const float*)d_in[7];
  const float* selb  = (const float*)d_in[8];
  const float* lng   = (const float*)d_in[9];
  const float* lnb   = (const float*)d_in[10];
  const float* headw = (const float*)d_in[11];
  const float* gum   = (const float*)d_in[12];
  float* out = (float*)d_out;

  char* ws = (char*)d_ws;
  __hip_bfloat16* w1t   = (__hip_bfloat16*)(ws);               // [8192,1024] bf16  16 MiB
  __hip_bfloat16* w2t   = (__hip_bfloat16*)(ws + 16777216);    // [1024,8192] bf16  16 MiB
  __hip_bfloat16* headb = (__hip_bfloat16*)(ws + 33554432);    // [32000,1024] bf16 62.5 MiB
  float*          h     = (float*)(ws + 99090432);             // [2048,1024] f32   8 MiB
  __hip_bfloat16* hb    = (__hip_bfloat16*)(ws + 107479040);   // [2048,1024] bf16  4 MiB
  __hip_bfloat16* u1    = (__hip_bfloat16*)(ws + 111673344);   // [2048,8192] bf16  32 MiB
  float*          W     = (float*)(ws + 145227776);            // [64,8]
  float*          wb2   = (float*)(ws + 145229824);            // [64,1024]
  float*          divp  = (float*)(ws + 145491968);            // scalar
  float*          part  = out;  // GEMM2 split-K partials: 4 x [2048,1024] f32 = 32 MiB,
                                // scratch inside d_out (256 MiB), overwritten by head GEMM later

  cvt_bf16_k<<<32000, 256, 0, stream>>>(headw, headb, 32768000L);
  tconv_k<<<dim3(32, 32, 8), dim3(32, 8), 0, stream>>>(w1, w1t, 1L << 20, 1024L, 1L << 20);
  tconv_k<<<dim3(32, 32, 8), dim3(32, 8), 0, stream>>>(w2, w2t, 1L << 20, 8192L, 1024L);
  embed_k<<<2048, 256, 0, stream>>>(x, emb, pos, h, hb, divp);

  for (int d = 0; d < 4; ++d) {
    select_k<<<64, 256, 0, stream>>>(h, selw, selb, gum, W, d);
    wb2_k<<<64, 256, 0, stream>>>(W, b2, wb2, divp);
    // u1' = W * gelu(h @ w1 + b1)   : M=2048 N=8192 K=1024
    gemm_nt<128, 128, 0><<<dim3(16, 64), 256, 0, stream>>>(hb, w1t, 1024, 1024, 8192, b1, W, nullptr, u1);
    // partials[z] = u1' @ w2 (K chunk z) : M=2048 N=1024 K=8192, split-K x4
    gemm_nt<64, 128, 2><<<dim3(32, 8, 4), 256, 0, stream>>>(u1, w2t, 8192, 2048, 1024, nullptr, nullptr, part, nullptr);
    h_update_k<<<2048, 256, 0, stream>>>(part, h, wb2, hb);
  }

  ln_k<<<2048, 256, 0, stream>>>(h, lng, lnb, hb, divp, out + 65536000L);
  // logits = hn @ head_w^T          : M=2048 N=32000 K=1024
  gemm_nt<128, 128, 2><<<dim3(16, 250), 256, 0, stream>>>(hb, headb, 1024, 1024, 32000, nullptr, nullptr, out, nullptr);
}